// Round 5
// baseline (75.157 us; speedup 1.0000x reference)
//
#include <hip/hip_runtime.h>

#define Bb 4
#define Cc 256
#define Ss 256
#define Hh 128
#define Ww 128
#define Jj 8
#define HWp 16384   // H*W
#define BN_EPS 1e-5f

// ---------------- workspace byte offsets ----------------
#define WS_PS   0          // 1024 f32 partial sums; REUSED after k_build as T[256] float4
#define WS_PQ   4096       // 1024 f32 partial sumsq
#define WS_MU   10240      // mu       4*8*256 f32 (32768 B)
#define WS_LAB  43008      // labels   4*128*128 u8 (65536 B)
#define WS_WTG  108544     // Wt_gamma 2304*256 f32 (2359296 B)
#define WS_WTB  2467840    // Wt_beta  2304*256 f32
#define WS_VT   4827136    // Vt [cc16][b4] slices of 13312 B = 851968 B

// Padded V-row: 16 ch * 4 B + 16 B pad = 80 B. j*80 mod 128 all-distinct -> conflict-free.
#define VROW 80
#define ZOFF 6480          // 81*80: z=1 (beta) byte offset inside a (cc,b) slice
#define SLICE_B 13312      // 2*6480 = 12960, padded to 13*1024 for width-16 staging
#define SLICE_F 3328       // floats

// ---- K1 (merged prep): bn-partial | labels | mu | transpose, split by blockIdx ----
__global__ void k_prep(const float* __restrict__ fp, const float* __restrict__ sg,
                       const float* __restrict__ style, const int* __restrict__ mask,
                       const float* __restrict__ Wmu, const float* __restrict__ bmu,
                       const float* __restrict__ Wg, const float* __restrict__ Wb,
                       float* __restrict__ ws_f, unsigned char* __restrict__ labout,
                       float* __restrict__ muout,
                       float* __restrict__ wtg, float* __restrict__ wtb) {
    __shared__ float smem[1056];           // max: transpose tile 32*33
    const int t = threadIdx.x;
    const int blk = blockIdx.x;
    if (blk < 1024) {
        // per-(c,b) partial sums for BN stats
        const int c = blk >> 2, b = blk & 3;
        const float4* s4 = (const float4*)(fp + (size_t)(b * Cc + c) * HWp);
        float sum = 0.f, sq = 0.f;
        #pragma unroll
        for (int k = 0; k < 16; ++k) {
            float4 v = s4[t + k * 256];
            sum += v.x + v.y + v.z + v.w;
            sq  += v.x * v.x + v.y * v.y + v.z * v.z + v.w * v.w;
        }
        float* ls = smem;
        float* lq = smem + 256;
        ls[t] = sum; lq[t] = sq;
        __syncthreads();
        for (int off = 128; off > 0; off >>= 1) {
            if (t < off) { ls[t] += ls[t + off]; lq[t] += lq[t + off]; }
            __syncthreads();
        }
        if (t == 0) { ws_f[blk] = ls[0]; ws_f[1024 + blk] = lq[0]; }
    } else if (blk < 1280) {
        // labels from one-hot sg
        const int i = (blk - 1024) * 256 + t;
        const int b = i >> 14, p = i & (HWp - 1);
        const float* base = sg + (size_t)b * Jj * HWp + p;
        int l = 0;
        #pragma unroll
        for (int j = 0; j < Jj; ++j)
            if (base[(size_t)j * HWp] > 0.5f) l = j;
        labout[i] = (unsigned char)l;
    } else if (blk < 1312) {
        // per-(b,j) style FC + ReLU -> mu
        const int lb = blk - 1280;
        const int b = lb >> 3, j = lb & 7;
        const int sel = (mask[b * Jj + j] == 1) ? j : Jj;
        float* code = smem;
        code[t] = style[(size_t)(b * (Jj + 1) + sel) * Ss + t];
        __syncthreads();
        const float4* wrow = (const float4*)(Wmu + (size_t)(j * Ss + t) * Ss);
        const float4* c4 = (const float4*)code;
        float acc = bmu[j * Ss + t];
        #pragma unroll 8
        for (int s4i = 0; s4i < Ss / 4; ++s4i) {
            float4 w = wrow[s4i]; float4 cv = c4[s4i];
            acc += w.x * cv.x + w.y * cv.y + w.z * cv.z + w.w * cv.w;
        }
        muout[(size_t)lb * Ss + t] = fmaxf(acc, 0.f);
    } else {
        // LDS-tiled transpose [256][2304] -> [2304][256]
        const int local = blk - 1312;            // 0..1151
        const int z = local / 576;
        const int rem = local % 576;
        const int k0 = (rem % 72) * 32;
        const int r0 = (rem / 72) * 32;
        const float* in = z ? Wb : Wg;
        float* outp = z ? wtb : wtg;
        float (*tile)[33] = (float(*)[33])smem;
        const int tx = t & 31, ty = t >> 5;
        #pragma unroll
        for (int i2 = 0; i2 < 4; ++i2)
            tile[ty + 8 * i2][tx] = in[(size_t)(r0 + ty + 8 * i2) * 2304 + k0 + tx];
        __syncthreads();
        #pragma unroll
        for (int i2 = 0; i2 < 4; ++i2)
            outp[(size_t)(k0 + ty + 8 * i2) * 256 + r0 + tx] = tile[tx][ty + 8 * i2];
    }
}

// ---- K2: blk 0 = BN finalize -> T table; blks 1..144 = Vt build (z x j-half split) ----
// Vt layout: [cc16][b][z][tap*9+j][20 f32 rows, 16 used]; row 8 of each tap = 0 sentinel.
__global__ void k_build(const float* __restrict__ bn_g, const float* __restrict__ bn_b,
                        const float* __restrict__ bgam, const float* __restrict__ bbet,
                        const float* __restrict__ wtg, const float* __restrict__ wtb,
                        const float* __restrict__ mu, float* __restrict__ ws_f,
                        float* __restrict__ vt) {
    const int t = threadIdx.x;
    if (blockIdx.x == 0) {
        // T[c] = (scale, shift, 1 + b_gamma, b_beta); overwrites PS region (safe:
        // each thread reads exactly floats [4t,4t+4) of PS before writing them)
        float s = 0.f, q = 0.f;
        #pragma unroll
        for (int b = 0; b < 4; ++b) { s += ws_f[t * 4 + b]; q += ws_f[1024 + t * 4 + b]; }
        float mean = s * (1.f / 65536.f);
        float var  = q * (1.f / 65536.f) - mean * mean;
        float sc = bn_g[t] * rsqrtf(var + BN_EPS);
        float sh = bn_b[t] - mean * sc;
        ((float4*)ws_f)[t] = make_float4(sc, sh, 1.f + bgam[t], bbet[t]);
        return;
    }
    const int lb = blockIdx.x - 1;          // 0..143
    const int z = lb / 72;
    const int rem = lb % 72;
    const int jh = rem / 36;                // j-half: j = jh*4 .. jh*4+3
    const int r2 = rem % 36;
    const int tap = r2 % 9, b = r2 / 9;
    const float* Wt = z ? wtb : wtg;
    __shared__ __align__(16) float ml[4 * Ss];           // ml[s*4+jj] = mu[b][jh*4+jj][s]
    for (int idx = t; idx < 4 * Ss; idx += 256)
        ml[idx] = mu[(size_t)b * Jj * Ss + (size_t)(jh * 4 + (idx & 3)) * Ss + (idx >> 2)];
    __syncthreads();
    float ag[4] = {0, 0, 0, 0};
    const float* wp = Wt + (size_t)tap * 256 + t;
    #pragma unroll 8
    for (int s = 0; s < Ss; ++s) {
        float wv = wp[(size_t)s * 2304];
        float4 m = *(const float4*)&ml[s * 4];
        ag[0] += wv * m.x; ag[1] += wv * m.y;
        ag[2] += wv * m.z; ag[3] += wv * m.w;
    }
    // channel c = t: cc group = t>>4, in-group channel = t&15
    const int cc = t >> 4, cl = t & 15;
    float* Vrow = vt + (size_t)(cc * 4 + b) * SLICE_F + z * 1620
                + (tap * 9 + jh * 4) * 20 + cl;
    #pragma unroll
    for (int jj = 0; jj < 4; ++jj) Vrow[jj * 20] = ag[jj];
    if (jh == 1) Vrow[4 * 20] = 0.f;        // OOB sentinel row (tap*9+8)
}

// ---- K3: fused BN-apply + conv-as-gather + SPADE combine, LDS-staged V ----
// Per block: 4 h-rows x 16 channels. (cc,b) V-slice (12960 B, 80-B padded rows)
// staged verbatim via 13 width-16 global_load_lds chunks. Gathers are ds_read_b128;
// j rows 80 B apart -> j*80 mod 128 all distinct -> conflict-free (j=8 2-way, free).
__global__ void __launch_bounds__(256, 8) k_main(
    const float* __restrict__ fp, const unsigned char* __restrict__ lab,
    const char* __restrict__ vt, const float4* __restrict__ T,
    float* __restrict__ out) {
    const int h0 = blockIdx.x * 4, cc = blockIdx.y, b = blockIdx.z;
    __shared__ __align__(16) char vbuf[SLICE_B];   // [z][81 rows][80 B]
    __shared__ int labs[6][132];
    __shared__ float4 Tl[16];
    const int t = threadIdx.x;
    const int lane = t & 63;
    const int wid = __builtin_amdgcn_readfirstlane(t >> 6);

    // stage the (cc,b) slice: 13 x 1024 B chunks (width 16), round-robin on waves
    {
        const char* slice = vt + (size_t)(cc * 4 + b) * SLICE_B;
        for (int r = wid; r < 13; r += 4) {
            __builtin_amdgcn_global_load_lds(
                (const __attribute__((address_space(1))) void*)(slice + r * 1024 + lane * 16),
                (__attribute__((address_space(3))) void*)(vbuf + r * 1024), 16, 0, 0);
        }
    }
    if (t < 16) Tl[t] = T[cc * 16 + t];
    for (int idx = t; idx < 6 * 132; idx += 256) {
        const int r = idx / 132, col = idx % 132 - 1;
        const int hh = h0 - 1 + r;
        int v = 8;                        // OOB sentinel -> zero row
        if (hh >= 0 && hh < Hh && col >= 0 && col < Ww)
            v = lab[((size_t)b << 14) + (hh << 7) + col];
        labs[r][idx % 132] = v;
    }
    __syncthreads();

    const int w = t & 127;
    const int cs = t >> 7;                 // 8-channel half (wave-uniform)
    const int cbase = cc * 16 + cs * 8;

    for (int hh = 0; hh < 4; ++hh) {
        int vb0[9];
        #pragma unroll
        for (int tap = 0; tap < 9; ++tap) {
            const int j = labs[hh + tap / 3][w + tap % 3];
            vb0[tap] = (tap * 9 + j) * VROW + cs * 32;
        }
        const size_t io = ((size_t)(b * Cc + cbase) << 14) + ((h0 + hh) << 7) + w;
        const float* fpp = fp + io;
        float* outp = out + io;
        #pragma unroll
        for (int cb = 0; cb < 2; ++cb) {
            float4 ga = make_float4(0.f, 0.f, 0.f, 0.f);
            float4 ea = make_float4(0.f, 0.f, 0.f, 0.f);
            #pragma unroll
            for (int tap = 0; tap < 9; ++tap) {
                const float4 vg = *(const float4*)(vbuf + vb0[tap] + cb * 16);
                const float4 ve = *(const float4*)(vbuf + ZOFF + vb0[tap] + cb * 16);
                ga.x += vg.x; ga.y += vg.y; ga.z += vg.z; ga.w += vg.w;
                ea.x += ve.x; ea.y += ve.y; ea.z += ve.z; ea.w += ve.w;
            }
            #define APPLY(CI, GV, EV)                                              \
            {                                                                      \
                const int c = cb * 4 + CI;                                         \
                const float4 tv = Tl[cs * 8 + c];                                  \
                const float f = __builtin_nontemporal_load(fpp + (size_t)c * HWp); \
                const float nf = fmaf(f, tv.x, tv.y);                              \
                __builtin_nontemporal_store(fmaf(nf, tv.z + (GV), tv.w + (EV)),    \
                                            outp + (size_t)c * HWp);               \
            }
            APPLY(0, ga.x, ea.x)
            APPLY(1, ga.y, ea.y)
            APPLY(2, ga.z, ea.z)
            APPLY(3, ga.w, ea.w)
            #undef APPLY
        }
    }
}

extern "C" void kernel_launch(void* const* d_in, const int* in_sizes, int n_in,
                              void* d_out, int out_size, void* d_ws, size_t ws_size,
                              hipStream_t stream) {
    const float* fp      = (const float*)d_in[0];
    const float* sg      = (const float*)d_in[1];
    const float* style   = (const float*)d_in[2];
    const int*   mask    = (const int*)d_in[3];
    const float* bn_g    = (const float*)d_in[4];
    const float* bn_b    = (const float*)d_in[5];
    const float* W_mu    = (const float*)d_in[6];
    const float* b_mu    = (const float*)d_in[7];
    const float* W_gam   = (const float*)d_in[8];
    const float* b_gam   = (const float*)d_in[9];
    const float* W_bet   = (const float*)d_in[10];
    const float* b_bet   = (const float*)d_in[11];
    float* out = (float*)d_out;

    char* ws = (char*)d_ws;
    float*         ws_f  = (float*)ws;
    unsigned char* labp  = (unsigned char*)(ws + WS_LAB);
    float*         mup   = (float*)(ws + WS_MU);
    float*         wtg   = (float*)(ws + WS_WTG);
    float*         wtb   = (float*)(ws + WS_WTB);
    float*         vtp   = (float*)(ws + WS_VT);

    k_prep<<<2464, 256, 0, stream>>>(fp, sg, style, mask, W_mu, b_mu, W_gam, W_bet,
                                     ws_f, labp, mup, wtg, wtb);
    k_build<<<145, 256, 0, stream>>>(bn_g, bn_b, b_gam, b_bet, wtg, wtb, mup, ws_f, vtp);
    k_main<<<dim3(32, 16, 4), 256, 0, stream>>>(fp, labp, (const char*)vtp,
                                                (const float4*)ws_f, out);
}

// Round 6
// 68.771 us; speedup vs baseline: 1.0928x; 1.0928x over previous
//
#include <hip/hip_runtime.h>

#define Bb 4
#define Cc 256
#define Ss 256
#define Hh 128
#define Ww 128
#define Jj 8
#define HWp 16384   // H*W
#define BN_EPS 1e-5f

// ---------------- workspace byte offsets ----------------
#define WS_PS   0          // 1024 f32 partial sums; REUSED after k_build as T[256] float4
#define WS_PQ   4096       // 1024 f32 partial sumsq
#define WS_MU   10240      // mu       4*8*256 f32 (32768 B)
#define WS_LAB  43008      // labels   4*128*128 u8 (65536 B)
#define WS_WTG  108544     // Wt_gamma 2304*256 f32 (2359296 B)
#define WS_WTB  2467840    // Wt_beta  2304*256 f32
#define WS_VT   4827136    // Vt [cc8][b4] slices of 22528 B = 720896 B

// V-row: [g: 32ch*4B | e: 32ch*4B | 16B pad] = 272 B. j*272B = j*68 dwords ->
// j*4 banks mod 32: {0,4,...,28} distinct for j=0..7; j=8 aliases j=0 (2-way, free).
#define VROW 272
#define SLICE_B 22528      // 81*272 = 22032, padded to 22*1024 for width-16 staging
#define SLICE_F 5632       // floats

// ---- K1 (merged prep): bn-partial | labels | mu | transpose, split by blockIdx ----
__global__ void k_prep(const float* __restrict__ fp, const float* __restrict__ sg,
                       const float* __restrict__ style, const int* __restrict__ mask,
                       const float* __restrict__ Wmu, const float* __restrict__ bmu,
                       const float* __restrict__ Wg, const float* __restrict__ Wb,
                       float* __restrict__ ws_f, unsigned char* __restrict__ labout,
                       float* __restrict__ muout,
                       float* __restrict__ wtg, float* __restrict__ wtb) {
    __shared__ float smem[1056];           // max: transpose tile 32*33
    const int t = threadIdx.x;
    const int blk = blockIdx.x;
    if (blk < 1024) {
        // per-(c,b) partial sums for BN stats
        const int c = blk >> 2, b = blk & 3;
        const float4* s4 = (const float4*)(fp + (size_t)(b * Cc + c) * HWp);
        float sum = 0.f, sq = 0.f;
        #pragma unroll
        for (int k = 0; k < 16; ++k) {
            float4 v = s4[t + k * 256];
            sum += v.x + v.y + v.z + v.w;
            sq  += v.x * v.x + v.y * v.y + v.z * v.z + v.w * v.w;
        }
        float* ls = smem;
        float* lq = smem + 256;
        ls[t] = sum; lq[t] = sq;
        __syncthreads();
        for (int off = 128; off > 0; off >>= 1) {
            if (t < off) { ls[t] += ls[t + off]; lq[t] += lq[t + off]; }
            __syncthreads();
        }
        if (t == 0) { ws_f[blk] = ls[0]; ws_f[1024 + blk] = lq[0]; }
    } else if (blk < 1280) {
        // labels from one-hot sg
        const int i = (blk - 1024) * 256 + t;
        const int b = i >> 14, p = i & (HWp - 1);
        const float* base = sg + (size_t)b * Jj * HWp + p;
        int l = 0;
        #pragma unroll
        for (int j = 0; j < Jj; ++j)
            if (base[(size_t)j * HWp] > 0.5f) l = j;
        labout[i] = (unsigned char)l;
    } else if (blk < 1312) {
        // per-(b,j) style FC + ReLU -> mu
        const int lb = blk - 1280;
        const int b = lb >> 3, j = lb & 7;
        const int sel = (mask[b * Jj + j] == 1) ? j : Jj;
        float* code = smem;
        code[t] = style[(size_t)(b * (Jj + 1) + sel) * Ss + t];
        __syncthreads();
        const float4* wrow = (const float4*)(Wmu + (size_t)(j * Ss + t) * Ss);
        const float4* c4 = (const float4*)code;
        float acc = bmu[j * Ss + t];
        #pragma unroll 8
        for (int s4i = 0; s4i < Ss / 4; ++s4i) {
            float4 w = wrow[s4i]; float4 cv = c4[s4i];
            acc += w.x * cv.x + w.y * cv.y + w.z * cv.z + w.w * cv.w;
        }
        muout[(size_t)lb * Ss + t] = fmaxf(acc, 0.f);
    } else {
        // LDS-tiled transpose [256][2304] -> [2304][256]
        const int local = blk - 1312;            // 0..1151
        const int z = local / 576;
        const int rem = local % 576;
        const int k0 = (rem % 72) * 32;
        const int r0 = (rem / 72) * 32;
        const float* in = z ? Wb : Wg;
        float* outp = z ? wtb : wtg;
        float (*tile)[33] = (float(*)[33])smem;
        const int tx = t & 31, ty = t >> 5;
        #pragma unroll
        for (int i2 = 0; i2 < 4; ++i2)
            tile[ty + 8 * i2][tx] = in[(size_t)(r0 + ty + 8 * i2) * 2304 + k0 + tx];
        __syncthreads();
        #pragma unroll
        for (int i2 = 0; i2 < 4; ++i2)
            outp[(size_t)(k0 + ty + 8 * i2) * 256 + r0 + tx] = tile[tx][ty + 8 * i2];
    }
}

// ---- K2: blk 0 = BN finalize -> T table; blks 1..72 = Vt build (z = g/e half) ----
// Vt layout: [cc8][b4] slice; row (tap*9+j) = [g 32ch | e 32ch | pad]; row 8 = 0.
__global__ void k_build(const float* __restrict__ bn_g, const float* __restrict__ bn_b,
                        const float* __restrict__ bgam, const float* __restrict__ bbet,
                        const float* __restrict__ wtg, const float* __restrict__ wtb,
                        const float* __restrict__ mu, float* __restrict__ ws_f,
                        float* __restrict__ vt) {
    const int t = threadIdx.x;
    if (blockIdx.x == 0) {
        // T[c] = (scale, shift, 1 + b_gamma, b_beta); overwrites PS region (safe:
        // each thread reads exactly floats [4t,4t+4) of PS before writing them)
        float s = 0.f, q = 0.f;
        #pragma unroll
        for (int b = 0; b < 4; ++b) { s += ws_f[t * 4 + b]; q += ws_f[1024 + t * 4 + b]; }
        float mean = s * (1.f / 65536.f);
        float var  = q * (1.f / 65536.f) - mean * mean;
        float sc = bn_g[t] * rsqrtf(var + BN_EPS);
        float sh = bn_b[t] - mean * sc;
        ((float4*)ws_f)[t] = make_float4(sc, sh, 1.f + bgam[t], bbet[t]);
        return;
    }
    const int lb = blockIdx.x - 1;          // 0..71
    const int z = lb / 36;
    const int rem = lb % 36;
    const int tap = rem % 9, b = rem / 9;
    const float* Wt = z ? wtb : wtg;
    __shared__ __align__(16) float ml[Jj * Ss];          // ml[s*8+j] = mu[b][j][s]
    for (int idx = t; idx < Jj * Ss; idx += 256)
        ml[idx] = mu[(size_t)b * Jj * Ss + (size_t)(idx & 7) * Ss + (idx >> 3)];
    __syncthreads();
    float ag[8] = {0,0,0,0,0,0,0,0};
    const float* wp = Wt + (size_t)tap * 256 + t;
    #pragma unroll 8
    for (int s = 0; s < Ss; ++s) {
        float wv = wp[(size_t)s * 2304];
        float4 m0 = *(const float4*)&ml[s * 8];
        float4 m1 = *(const float4*)&ml[s * 8 + 4];
        ag[0] += wv * m0.x; ag[1] += wv * m0.y;
        ag[2] += wv * m0.z; ag[3] += wv * m0.w;
        ag[4] += wv * m1.x; ag[5] += wv * m1.y;
        ag[6] += wv * m1.z; ag[7] += wv * m1.w;
    }
    // channel c = t: cc group = t>>5, in-group channel = t&31
    const int cc = t >> 5, cl = t & 31;
    float* base = vt + (size_t)(cc * 4 + b) * SLICE_F + z * 32 + cl;
    #pragma unroll
    for (int j = 0; j < 8; ++j) base[(tap * 9 + j) * 68] = ag[j];
    base[(tap * 9 + 8) * 68] = 0.f;         // OOB sentinel row (each z zeros its half)
}

// ---- K3: fused BN-apply + conv-as-gather + SPADE combine, LDS-staged V ----
// Per block: 2 h-rows x 32 channels. (cc,b) slice (22 KB, g|e interleaved rows)
// staged verbatim via 22 width-16 global_load_lds chunks. Per cb: two 9-read
// ds_read_b128 windows (g then e) pinned by sched_barrier -> ~36-reg MLP window
// while staying in the <=64-VGPR / 8-wave occupancy band.
__global__ void __launch_bounds__(256, 8) k_main(
    const float* __restrict__ fp, const unsigned char* __restrict__ lab,
    const char* __restrict__ vt, const float4* __restrict__ T,
    float* __restrict__ out) {
    const int h0 = blockIdx.x * 2, cc = blockIdx.y, b = blockIdx.z;
    __shared__ __align__(16) char vbuf[SLICE_B];   // [81 rows][272 B]
    __shared__ int labs[4][132];
    __shared__ float4 Tl[32];
    const int t = threadIdx.x;
    const int lane = t & 63;
    const int wid = __builtin_amdgcn_readfirstlane(t >> 6);

    // stage the (cc,b) slice: 22 x 1024 B chunks (width 16), round-robin on waves
    {
        const char* slice = vt + (size_t)(cc * 4 + b) * SLICE_B;
        for (int r = wid; r < 22; r += 4) {
            __builtin_amdgcn_global_load_lds(
                (const __attribute__((address_space(1))) void*)(slice + r * 1024 + lane * 16),
                (__attribute__((address_space(3))) void*)(vbuf + r * 1024), 16, 0, 0);
        }
    }
    if (t < 32) Tl[t] = T[cc * 32 + t];
    for (int idx = t; idx < 4 * 132; idx += 256) {
        const int r = idx / 132, col = idx % 132 - 1;
        const int hh = h0 - 1 + r;
        int v = 8;                        // OOB sentinel -> zero row
        if (hh >= 0 && hh < Hh && col >= 0 && col < Ww)
            v = lab[((size_t)b << 14) + (hh << 7) + col];
        labs[r][idx % 132] = v;
    }
    __syncthreads();

    const int w = t & 127;
    const int cs = t >> 7;                 // 16-channel half (wave-uniform)
    const int cbase = cc * 32 + cs * 16;

    for (int hh = 0; hh < 2; ++hh) {
        int vb0[9];
        #pragma unroll
        for (int tap = 0; tap < 9; ++tap) {
            const int j = labs[hh + tap / 3][w + tap % 3];
            vb0[tap] = (tap * 9 + j) * VROW + cs * 64;
        }
        const size_t io = ((size_t)(b * Cc + cbase) << 14) + ((h0 + hh) << 7) + w;
        const float* fpp = fp + io;
        float* outp = out + io;
        #pragma unroll
        for (int cb = 0; cb < 4; ++cb) {
            // ---- gamma window: 9 x ds_read_b128 ----
            float4 vg[9];
            #pragma unroll
            for (int tap = 0; tap < 9; ++tap)
                vg[tap] = *(const float4*)(vbuf + vb0[tap] + cb * 16);
            __builtin_amdgcn_sched_barrier(0);
            // ---- beta window issues while gamma sums retire ----
            float4 ve[9];
            #pragma unroll
            for (int tap = 0; tap < 9; ++tap)
                ve[tap] = *(const float4*)(vbuf + vb0[tap] + 128 + cb * 16);
            float4 ga;
            ga.x = ((vg[0].x + vg[1].x) + (vg[2].x + vg[3].x)) +
                   ((vg[4].x + vg[5].x) + (vg[6].x + vg[7].x)) + vg[8].x;
            ga.y = ((vg[0].y + vg[1].y) + (vg[2].y + vg[3].y)) +
                   ((vg[4].y + vg[5].y) + (vg[6].y + vg[7].y)) + vg[8].y;
            ga.z = ((vg[0].z + vg[1].z) + (vg[2].z + vg[3].z)) +
                   ((vg[4].z + vg[5].z) + (vg[6].z + vg[7].z)) + vg[8].z;
            ga.w = ((vg[0].w + vg[1].w) + (vg[2].w + vg[3].w)) +
                   ((vg[4].w + vg[5].w) + (vg[6].w + vg[7].w)) + vg[8].w;
            __builtin_amdgcn_sched_barrier(0);
            float4 ea;
            ea.x = ((ve[0].x + ve[1].x) + (ve[2].x + ve[3].x)) +
                   ((ve[4].x + ve[5].x) + (ve[6].x + ve[7].x)) + ve[8].x;
            ea.y = ((ve[0].y + ve[1].y) + (ve[2].y + ve[3].y)) +
                   ((ve[4].y + ve[5].y) + (ve[6].y + ve[7].y)) + ve[8].y;
            ea.z = ((ve[0].z + ve[1].z) + (ve[2].z + ve[3].z)) +
                   ((ve[4].z + ve[5].z) + (ve[6].z + ve[7].z)) + ve[8].z;
            ea.w = ((ve[0].w + ve[1].w) + (ve[2].w + ve[3].w)) +
                   ((ve[4].w + ve[5].w) + (ve[6].w + ve[7].w)) + ve[8].w;
            #define APPLY(CI, GV, EV)                                              \
            {                                                                      \
                const int c = cb * 4 + CI;                                         \
                const float4 tv = Tl[cs * 16 + c];                                 \
                const float f = __builtin_nontemporal_load(fpp + (size_t)c * HWp); \
                const float nf = fmaf(f, tv.x, tv.y);                              \
                __builtin_nontemporal_store(fmaf(nf, tv.z + (GV), tv.w + (EV)),    \
                                            outp + (size_t)c * HWp);               \
            }
            APPLY(0, ga.x, ea.x)
            APPLY(1, ga.y, ea.y)
            APPLY(2, ga.z, ea.z)
            APPLY(3, ga.w, ea.w)
            #undef APPLY
        }
    }
}

extern "C" void kernel_launch(void* const* d_in, const int* in_sizes, int n_in,
                              void* d_out, int out_size, void* d_ws, size_t ws_size,
                              hipStream_t stream) {
    const float* fp      = (const float*)d_in[0];
    const float* sg      = (const float*)d_in[1];
    const float* style   = (const float*)d_in[2];
    const int*   mask    = (const int*)d_in[3];
    const float* bn_g    = (const float*)d_in[4];
    const float* bn_b    = (const float*)d_in[5];
    const float* W_mu    = (const float*)d_in[6];
    const float* b_mu    = (const float*)d_in[7];
    const float* W_gam   = (const float*)d_in[8];
    const float* b_gam   = (const float*)d_in[9];
    const float* W_bet   = (const float*)d_in[10];
    const float* b_bet   = (const float*)d_in[11];
    float* out = (float*)d_out;

    char* ws = (char*)d_ws;
    float*         ws_f  = (float*)ws;
    unsigned char* labp  = (unsigned char*)(ws + WS_LAB);
    float*         mup   = (float*)(ws + WS_MU);
    float*         wtg   = (float*)(ws + WS_WTG);
    float*         wtb   = (float*)(ws + WS_WTB);
    float*         vtp   = (float*)(ws + WS_VT);

    k_prep<<<2464, 256, 0, stream>>>(fp, sg, style, mask, W_mu, b_mu, W_gam, W_bet,
                                     ws_f, labp, mup, wtg, wtb);
    k_build<<<73, 256, 0, stream>>>(bn_g, bn_b, b_gam, b_bet, wtg, wtb, mup, ws_f, vtp);
    k_main<<<dim3(64, 8, 4), 256, 0, stream>>>(fp, labp, (const char*)vtp,
                                               (const float4*)ws_f, out);
}